// Round 2
// baseline (315.591 us; speedup 1.0000x reference)
//
#include <hip/hip_runtime.h>

#define NPTS 16384
#define KNN 16
#define HID 64
#define NCLS 10

#define WPB 4              // waves per block (knn)
#define QPB 16             // queries per block, shared by all waves
#define CPW (NPTS / WPB)   // candidates per wave = 4096
#define SCAP 128           // per-query survivor capacity (block-shared LDS list)

// dist chain (3 fmaf): pm2 holds (-2x,-2y,-2z,|p|^2); query supplies raw (x,y,z).
// d = |p|^2 - 2 p.q  (sq_q dropped: rank-invariant per query). Identical chain
// everywhere so τ comparisons are bit-exact across phases.
__device__ __forceinline__ float distm2(float qx, float qy, float qz, float4 c) {
    return fmaf(qx, c.x, fmaf(qy, c.y, fmaf(qz, c.z, c.w)));
}

// wave-uniform float -> SGPR (frees VGPRs; 1 SGPR operand per VALU op is legal)
__device__ __forceinline__ float __frfl(float x) {
    return __int_as_float(__builtin_amdgcn_readfirstlane(__float_as_int(x)));
}

// monotone float->u32, packed with index: ascending u64 order == (d asc, j asc)
__device__ __forceinline__ unsigned long long dkey(float v, int j) {
    unsigned u = __float_as_uint(v);
    u = (u & 0x80000000u) ? ~u : (u | 0x80000000u);
    return ((unsigned long long)u << 32) | (unsigned)j;
}

__device__ __forceinline__ unsigned long long shfl_xor_u64(unsigned long long x, int m) {
    unsigned hi = (unsigned)__shfl_xor((int)(x >> 32), m, 64);
    unsigned lo = (unsigned)__shfl_xor((int)(x & 0xffffffffu), m, 64);
    return ((unsigned long long)hi << 32) | lo;
}

// exact wave-wide top-16 (overflow slow path only)
__device__ __forceinline__ void wave_top16_16(unsigned long long (&key)[16], int lane,
                                              int q, int* __restrict__ idx) {
    int outj = 0x7fffffff;
    for (int r = 0; r < 16; ++r) {
        unsigned long long gm = key[0];
#pragma unroll
        for (int s = 1; s < 16; ++s) gm = key[s] < gm ? key[s] : gm;
#pragma unroll
        for (int st = 1; st < 64; st <<= 1) {
            unsigned long long o = shfl_xor_u64(gm, st);
            gm = o < gm ? o : gm;
        }
        if (lane == r) outj = (int)(gm & 0xffffffffu);
#pragma unroll
        for (int s = 0; s < 16; ++s)
            if (key[s] == gm) key[s] = ~0ull;
    }
    if (lane < 16) idx[q * KNN + lane] = outj;
}

// pos (N,3) -> pos4 (x,y,z,|p|^2) and pm2 (-2x,-2y,-2z,|p|^2)
__global__ void prep_kernel(const float* __restrict__ pos, float4* __restrict__ pos4,
                            float4* __restrict__ pm2) {
    int i = blockIdx.x * 256 + threadIdx.x;
    if (i < NPTS) {
        float x = pos[3 * i], y = pos[3 * i + 1], z = pos[3 * i + 2];
        float sq = fmaf(x, x, fmaf(y, y, z * z));
        pos4[i] = make_float4(x, y, z, sq);
        pm2[i] = make_float4(-2.f * x, -2.f * y, -2.f * z, sq);
    }
}

// CANDIDATE-SPLIT kNN + 2-deep prefetch + merged branch tests.
// Block = 4 waves sharing 16 queries (SGPR-pinned); wave w scans its quarter.
// Phase A: per-lane minima; per-wave stream minima combined in LDS -> tight tau.
// Phase B: tau-filtered push of (d,j) keys into block-shared per-query lists.
// Extraction: rank-select, 8-wide MLP; ranks 0..15 unique under (d,j) tie-break.
__global__ __launch_bounds__(256) void knn_kernel(const float4* __restrict__ pos4,
                                                  const float4* __restrict__ pm2,
                                                  int* __restrict__ idx) {
    __shared__ unsigned long long keys[QPB][SCAP];   // 16KB
    __shared__ int knt[QPB];
    __shared__ float smin[QPB][WPB][16];             // 4KB
    int tid = threadIdx.x;
    int lane = tid & 63;
    int w = tid >> 6;
    int qb = blockIdx.x * QPB;
    float qx[QPB], qy[QPB], qz[QPB];
#pragma unroll
    for (int i = 0; i < QPB; ++i) {
        float4 t4 = pos4[qb + i];          // wave-uniform
        qx[i] = __frfl(t4.x); qy[i] = __frfl(t4.y); qz[i] = __frfl(t4.z);
    }
    int base = w * CPW;

    // ---- Phase A: per-lane minima, 2-deep register prefetch ----
    float mn[QPB];
#pragma unroll
    for (int i = 0; i < QPB; ++i) mn[i] = INFINITY;
    {
        float4 c0 = pm2[base + lane],       c1 = pm2[base + 64 + lane];
        float4 d0 = pm2[base + 128 + lane], d1 = pm2[base + 192 + lane];
        for (int cb = base; cb < base + CPW; cb += 128) {
#pragma unroll
            for (int i = 0; i < QPB; ++i) {
                float va = distm2(qx[i], qy[i], qz[i], c0);
                float vb = distm2(qx[i], qy[i], qz[i], c1);
                mn[i] = fminf(mn[i], fminf(va, vb));   // fuses to v_min3_f32
            }
            c0 = d0; c1 = d1;
            d0 = pm2[cb + 256 + lane];      // pad (+256) makes last iters safe
            d1 = pm2[cb + 320 + lane];
        }
    }
    // per-wave stream minima (stream = lane mod 16) -> LDS
#pragma unroll
    for (int i = 0; i < QPB; ++i) {
        float m = mn[i];
        m = fminf(m, __shfl_xor(m, 16, 64));
        m = fminf(m, __shfl_xor(m, 32, 64));
        if (lane < 16) smin[i][w][lane] = m;
    }
    if (tid < QPB) knt[tid] = 0;
    __syncthreads();   // barrier 1: smin + knt visible

    // tight tau from full-N stream minima (combine the 4 wave quarters)
    float tq[QPB];
#pragma unroll
    for (int i = 0; i < QPB; ++i) {
        int s = lane & 15;
        float m = fminf(fminf(smin[i][0][s], smin[i][1][s]),
                        fminf(smin[i][2][s], smin[i][3][s]));
        m = fmaxf(m, __shfl_xor(m, 1, 64));
        m = fmaxf(m, __shfl_xor(m, 2, 64));
        m = fmaxf(m, __shfl_xor(m, 4, 64));
        m = fmaxf(m, __shfl_xor(m, 8, 64));
        tq[i] = __frfl(m);                  // wave-uniform -> SGPR
    }

    // ---- Phase B: tau-filtered push, merged (2-candidate) branch tests ----
    {
        float4 c0 = pm2[base + lane],       c1 = pm2[base + 64 + lane];
        float4 d0 = pm2[base + 128 + lane], d1 = pm2[base + 192 + lane];
        for (int cb = base; cb < base + CPW; cb += 128) {
            int j0 = cb + lane, j1 = cb + 64 + lane;
#pragma unroll
            for (int i = 0; i < QPB; ++i) {
                float va = distm2(qx[i], qy[i], qz[i], c0);
                float vb = distm2(qx[i], qy[i], qz[i], c1);
                if (fminf(va, vb) <= tq[i]) {           // 16 branches/iter not 32
                    if (va <= tq[i]) { int s = atomicAdd(&knt[i], 1); if (s < SCAP) keys[i][s] = dkey(va, j0); }
                    if (vb <= tq[i]) { int s = atomicAdd(&knt[i], 1); if (s < SCAP) keys[i][s] = dkey(vb, j1); }
                }
            }
            c0 = d0; c1 = d1;
            d0 = pm2[cb + 256 + lane];
            d1 = pm2[cb + 320 + lane];
        }
    }
    __syncthreads();   // barrier 2: all pushes visible

    // ---- Extraction: wave w handles queries 4w..4w+3, 8-wide rank loop ----
#pragma unroll
    for (int e = 0; e < 4; ++e) {
        int qi = w * 4 + e;
        int q = qb + qi;
        int ntot = knt[qi];
        if (ntot <= SCAP) {
            unsigned long long k0 = (lane < ntot) ? keys[qi][lane] : ~0ull;
            unsigned long long k1 = (lane + 64 < ntot) ? keys[qi][lane + 64] : ~0ull;
            int r0 = 0, r1 = 0;
            int t = 0;
            for (; t + 8 <= ntot; t += 8) {             // 8 independent ds_reads in flight
                unsigned long long a0 = keys[qi][t + 0], a1 = keys[qi][t + 1];
                unsigned long long a2 = keys[qi][t + 2], a3 = keys[qi][t + 3];
                unsigned long long a4 = keys[qi][t + 4], a5 = keys[qi][t + 5];
                unsigned long long a6 = keys[qi][t + 6], a7 = keys[qi][t + 7];
                r0 += (int)(a0 < k0) + (int)(a1 < k0) + (int)(a2 < k0) + (int)(a3 < k0)
                    + (int)(a4 < k0) + (int)(a5 < k0) + (int)(a6 < k0) + (int)(a7 < k0);
                r1 += (int)(a0 < k1) + (int)(a1 < k1) + (int)(a2 < k1) + (int)(a3 < k1)
                    + (int)(a4 < k1) + (int)(a5 < k1) + (int)(a6 < k1) + (int)(a7 < k1);
            }
            for (; t < ntot; ++t) {
                unsigned long long k = keys[qi][t];
                r0 += (int)(k < k0);
                r1 += (int)(k < k1);
            }
            if (lane < ntot && r0 < KNN) idx[q * KNN + r0] = (int)(k0 & 0xffffffffu);
            if (lane + 64 < ntot && r1 < KNN) idx[q * KNN + r1] = (int)(k1 & 0xffffffffu);
        } else {
            // overflow (astronomically rare with tight tau): exact full rescan
            float tqq = tq[qi];
            unsigned long long key[16];
#pragma unroll
            for (int u = 0; u < 16; ++u) key[u] = ~0ull;
            for (int j = lane; j < NPTS; j += 64) {
                float v = distm2(qx[qi], qy[qi], qz[qi], pm2[j]);
                unsigned long long k = dkey(v, j);
                if (v <= tqq && k < key[15]) {
#pragma unroll
                    for (int s = 0; s < 16; ++s) {
                        unsigned long long a = k < key[s] ? k : key[s];
                        unsigned long long b = k < key[s] ? key[s] : k;
                        key[s] = a;
                        k = b;
                    }
                }
            }
            wave_top16_16(key, lane, q, idx);
        }
    }
}

// FUSED EdgeConv1 + ec2_pre (both pointwise in p; h1 never touches global).
// Wave handles 4 points: compute h1 into LDS, then C2/Y2 from LDS broadcasts.
// Neighbor gather: idx row batched as 4x int4, then 16 independent pos4 loads.
__global__ __launch_bounds__(256) void ec12_kernel(const float4* __restrict__ pos4,
                                                   const int* __restrict__ idx,
                                                   const float* __restrict__ W1,
                                                   const float* __restrict__ b1,
                                                   const float* __restrict__ W2,
                                                   const float* __restrict__ b2,
                                                   float* __restrict__ C2,
                                                   float* __restrict__ Y2) {
    __shared__ float h1s[16][64];    // 4KB, [w*4+i][t], wave-private slices
    int t = threadIdx.x & 63;
    int w = threadIdx.x >> 6;
    int pb = blockIdx.x * 16 + w * 4;
    float w0 = W1[0 * HID + t], w1 = W1[1 * HID + t], w2 = W1[2 * HID + t];
    float v0 = W1[3 * HID + t], v1 = W1[4 * HID + t], v2 = W1[5 * HID + t];
    float bt1 = b1[t];
#pragma unroll
    for (int i = 0; i < 4; ++i) {
        int p = pb + i;
        float4 xi = pos4[p];
        float C = bt1 + xi.x * (w0 - v0) + xi.y * (w1 - v1) + xi.z * (w2 - v2);
        const int4* ip = (const int4*)(idx + (size_t)p * KNN);
        int4 n0 = ip[0], n1 = ip[1], n2 = ip[2], n3 = ip[3];   // 4 parallel loads
        int jj[16] = {n0.x, n0.y, n0.z, n0.w, n1.x, n1.y, n1.z, n1.w,
                      n2.x, n2.y, n2.z, n2.w, n3.x, n3.y, n3.z, n3.w};
        float m = -INFINITY;
#pragma unroll
        for (int k = 0; k < KNN; ++k) {
            float4 xj = pos4[jj[k]];      // 16 mutually-independent uniform loads
            m = fmaxf(m, fmaf(xj.x, v0, fmaf(xj.y, v1, xj.z * v2)));
        }
        h1s[w * 4 + i][t] = fmaxf(C + m, 0.f);
    }
    __syncthreads();
    float aa[4] = {0.f, 0.f, 0.f, 0.f};
    float ab[4] = {0.f, 0.f, 0.f, 0.f};
#pragma unroll 8
    for (int f = 0; f < 64; ++f) {
        float wa = W2[f * HID + t];
        float wb = W2[(64 + f) * HID + t];
#pragma unroll
        for (int i = 0; i < 4; ++i) {
            float h = h1s[w * 4 + i][f];   // broadcast ds_read
            aa[i] = fmaf(h, wa, aa[i]);
            ab[i] = fmaf(h, wb, ab[i]);
        }
    }
    float bt = b2[t];
#pragma unroll
    for (int i = 0; i < 4; ++i) {
        C2[(pb + i) * HID + t] = bt + aa[i] - ab[i];
        Y2[(pb + i) * HID + t] = ab[i];
    }
}

// ec2_maxpool: val = relu(C2 + max_k Y2[idx[k]]); block-partial max-pool.
__global__ __launch_bounds__(256) void ec2_maxpool_kernel(const float* __restrict__ C2,
                                                          const float* __restrict__ Y2,
                                                          const int* __restrict__ idx,
                                                          float* __restrict__ gpartial) {
    int t = threadIdx.x & 63;
    int lp = threadIdx.x >> 6;
    int p = blockIdx.x * 4 + lp;
    const int4* ip = (const int4*)(idx + (size_t)p * KNN);
    int4 n0 = ip[0], n1 = ip[1], n2 = ip[2], n3 = ip[3];
    int jj[16] = {n0.x, n0.y, n0.z, n0.w, n1.x, n1.y, n1.z, n1.w,
                  n2.x, n2.y, n2.z, n2.w, n3.x, n3.y, n3.z, n3.w};
    float m = -INFINITY;
#pragma unroll
    for (int k = 0; k < KNN; ++k) {
        m = fmaxf(m, Y2[jj[k] * HID + t]);   // 16 independent gathers
    }
    float val = fmaxf(C2[p * HID + t] + m, 0.f);
    __shared__ float red[4][64];
    red[lp][t] = val;
    __syncthreads();
    if (lp == 0) {
        float g = fmaxf(fmaxf(red[0][t], red[1][t]), fmaxf(red[2][t], red[3][t]));
        gpartial[blockIdx.x * 64 + t] = g;
    }
}

// greduce2: 4096 -> 256 partial rows, fully coalesced, 256 parallel blocks.
__global__ __launch_bounds__(256) void greduce2_kernel(const float* __restrict__ gpartial,
                                                       float* __restrict__ gp2) {
    __shared__ float red[4][64];
    int f = threadIdx.x & 63;
    int w = threadIdx.x >> 6;
    int r0 = blockIdx.x * 16 + w * 4;
    float m = -INFINITY;
#pragma unroll
    for (int r = 0; r < 4; ++r) m = fmaxf(m, gpartial[(r0 + r) * 64 + f]);
    red[w][f] = m;
    __syncthreads();
    if (w == 0)
        gp2[blockIdx.x * 64 + f] =
            fmaxf(fmaxf(red[0][f], red[1][f]), fmaxf(red[2][f], red[3][f]));
}

// tail2: 256 rows -> g[64], then linear head. One block (cheap now).
__global__ __launch_bounds__(256) void tail2_kernel(const float* __restrict__ gp2,
                                                    const float* __restrict__ Wc,
                                                    const float* __restrict__ bc,
                                                    float* __restrict__ out) {
    __shared__ float red[4][64];
    __shared__ float g[64];
    int f = threadIdx.x & 63;
    int w = threadIdx.x >> 6;
    float m = -INFINITY;
    for (int i = w; i < 256; i += 4) m = fmaxf(m, gp2[i * 64 + f]);
    red[w][f] = m;
    __syncthreads();
    if (w == 0) g[f] = fmaxf(fmaxf(red[0][f], red[1][f]), fmaxf(red[2][f], red[3][f]));
    __syncthreads();
    if (threadIdx.x < NCLS) {
        float a = bc[threadIdx.x];
#pragma unroll
        for (int h = 0; h < HID; ++h) a = fmaf(g[h], Wc[h * NCLS + threadIdx.x], a);
        out[threadIdx.x] = a;
    }
}

extern "C" void kernel_launch(void* const* d_in, const int* in_sizes, int n_in,
                              void* d_out, int out_size, void* d_ws, size_t ws_size,
                              hipStream_t stream) {
    const float* pos = (const float*)d_in[0];
    // d_in[1] = batch (all zeros, num_segments=1) -> unused
    const float* W1 = (const float*)d_in[2];
    const float* b1 = (const float*)d_in[3];
    const float* W2 = (const float*)d_in[4];
    const float* b2 = (const float*)d_in[5];
    const float* Wc = (const float*)d_in[6];
    const float* bc = (const float*)d_in[7];
    float* out = (float*)d_out;

    char* ws = (char*)d_ws;
    size_t o = 0;
    auto alloc = [&](size_t bytes) { size_t r = o; o += (bytes + 255) & ~size_t(255); return r; };
    size_t fm = (size_t)NPTS * HID * 4;
    size_t o_pos4 = alloc((size_t)NPTS * 16);
    size_t o_pm2 = alloc((size_t)(NPTS + 320) * 16);   // +320 prefetch pad
    size_t o_idx = alloc((size_t)NPTS * KNN * 4);
    size_t o_C2 = alloc(fm);
    size_t o_Y2 = alloc(fm);
    size_t o_gp = alloc((size_t)(NPTS / 4) * HID * 4);
    size_t o_gp2 = alloc((size_t)256 * HID * 4);

    float4* pos4 = (float4*)(ws + o_pos4);
    float4* pm2 = (float4*)(ws + o_pm2);
    int* idx = (int*)(ws + o_idx);
    float* C2 = (float*)(ws + o_C2);
    float* Y2 = (float*)(ws + o_Y2);
    float* gp = (float*)(ws + o_gp);
    float* gp2 = (float*)(ws + o_gp2);

    // zero the prefetch pad (loaded but never consumed)
    hipMemsetAsync(pm2 + NPTS, 0, 320 * sizeof(float4), stream);

    prep_kernel<<<NPTS / 256, 256, 0, stream>>>(pos, pos4, pm2);
    knn_kernel<<<NPTS / QPB, 256, 0, stream>>>(pos4, pm2, idx);
    ec12_kernel<<<NPTS / 16, 256, 0, stream>>>(pos4, idx, W1, b1, W2, b2, C2, Y2);
    ec2_maxpool_kernel<<<NPTS / 4, 256, 0, stream>>>(C2, Y2, idx, gp);
    greduce2_kernel<<<256, 256, 0, stream>>>(gp, gp2);
    tail2_kernel<<<1, 256, 0, stream>>>(gp2, Wc, bc, out);
}

// Round 3
// 301.352 us; speedup vs baseline: 1.0472x; 1.0472x over previous
//
#include <hip/hip_runtime.h>

#define NPTS 16384
#define KNN 16
#define HID 64
#define NCLS 10

#define WPB 4              // waves per block (knn)
#define QPB 8              // queries per block, shared by all waves
#define SCAP 128           // per-query survivor capacity (block-shared LDS list)
// pair-space geometry: candidates come in pairs (2p, 2p+1); a wave's quarter is
// 2048 pairs = 32 groups of 64 pairs. Per iter a lane handles 2 pair-slots.
#define GRPQ 32            // groups per wave quarter
#define NITER 16           // iters per phase (2 groups per iter)
#define TPAD 576           // pm2t prefetch pad (float4), max overrun 512

typedef float v2f __attribute__((ext_vector_type(2)));

// packed distance: D = {d(c0), d(c1)} = Qx*X + Qy*Y + Qz*Z + W  (3 pk_fma)
__device__ __forceinline__ v2f pdist(v2f Qx, v2f Qy, v2f Qz, v2f X, v2f Y, v2f Z, v2f W) {
    return __builtin_elementwise_fma(Qx, X,
            __builtin_elementwise_fma(Qy, Y,
             __builtin_elementwise_fma(Qz, Z, W)));
}

// scalar twin (overflow path) — identical op order => bit-exact vs packed halves
__device__ __forceinline__ float distm2(float qx, float qy, float qz, float4 c) {
    return fmaf(qx, c.x, fmaf(qy, c.y, fmaf(qz, c.z, c.w)));
}

// wave-uniform float -> SGPR
__device__ __forceinline__ float __frfl(float x) {
    return __int_as_float(__builtin_amdgcn_readfirstlane(__float_as_int(x)));
}

// monotone float->u32, packed with index: ascending u64 order == (d asc, j asc)
__device__ __forceinline__ unsigned long long dkey(float v, int j) {
    unsigned u = __float_as_uint(v);
    u = (u & 0x80000000u) ? ~u : (u | 0x80000000u);
    return ((unsigned long long)u << 32) | (unsigned)j;
}

__device__ __forceinline__ unsigned long long shfl_xor_u64(unsigned long long x, int m) {
    unsigned hi = (unsigned)__shfl_xor((int)(x >> 32), m, 64);
    unsigned lo = (unsigned)__shfl_xor((int)(x & 0xffffffffu), m, 64);
    return ((unsigned long long)hi << 32) | lo;
}

// exact wave-wide top-16 (overflow slow path only)
__device__ __forceinline__ void wave_top16_16(unsigned long long (&key)[16], int lane,
                                              int q, int* __restrict__ idx) {
    int outj = 0x7fffffff;
    for (int r = 0; r < 16; ++r) {
        unsigned long long gm = key[0];
#pragma unroll
        for (int s = 1; s < 16; ++s) gm = key[s] < gm ? key[s] : gm;
#pragma unroll
        for (int st = 1; st < 64; st <<= 1) {
            unsigned long long o = shfl_xor_u64(gm, st);
            gm = o < gm ? o : gm;
        }
        if (lane == r) outj = (int)(gm & 0xffffffffu);
#pragma unroll
        for (int s = 0; s < 16; ++s)
            if (key[s] == gm) key[s] = ~0ull;
    }
    if (lane < 16) idx[q * KNN + lane] = outj;
}

// pos (N,3) -> pos4 (x,y,z,|p|^2), pm2 (-2x,-2y,-2z,|p|^2) [overflow path],
// pm2t pair-transposed: group g (64 pairs): [g*128+l]=(x0,x1,y0,y1) of pair g*64+l,
//                                           [g*128+64+l]=(z0,z1,w0,w1)
__global__ void prep_kernel(const float* __restrict__ pos, float4* __restrict__ pos4,
                            float4* __restrict__ pm2, float4* __restrict__ pm2t) {
    int i = blockIdx.x * 256 + threadIdx.x;
    if (i < NPTS) {
        float x = pos[3 * i], y = pos[3 * i + 1], z = pos[3 * i + 2];
        float sq = fmaf(x, x, fmaf(y, y, z * z));
        pos4[i] = make_float4(x, y, z, sq);
        pm2[i] = make_float4(-2.f * x, -2.f * y, -2.f * z, sq);
    }
    if (i < NPTS / 2) {
        int p = i;                       // pair p = candidates 2p, 2p+1
        float x0 = pos[6 * p],     y0 = pos[6 * p + 1], z0 = pos[6 * p + 2];
        float x1 = pos[6 * p + 3], y1 = pos[6 * p + 4], z1 = pos[6 * p + 5];
        float w0 = fmaf(x0, x0, fmaf(y0, y0, z0 * z0));
        float w1 = fmaf(x1, x1, fmaf(y1, y1, z1 * z1));
        int g = p >> 6, l = p & 63;
        pm2t[g * 128 + l]      = make_float4(-2.f * x0, -2.f * x1, -2.f * y0, -2.f * y1);
        pm2t[g * 128 + 64 + l] = make_float4(-2.f * z0, -2.f * z1, w0, w1);
    }
}

// CANDIDATE-SPLIT kNN, packed-FP32 distance core (v_pk_fma_f32).
// Block = 4 waves sharing 8 queries (SGPR-broadcast pairs); wave scans its quarter.
// Phase A: per-lane packed minima -> stream minima -> tight tau.
// Phase B: tau-filtered push (one __any branch per query per iter).
__global__ __launch_bounds__(256) void knn_kernel(const float4* __restrict__ pos4,
                                                  const float4* __restrict__ pm2,
                                                  const float4* __restrict__ pm2t,
                                                  int* __restrict__ idx) {
    __shared__ unsigned long long keys[QPB][SCAP];   // 8KB
    __shared__ int knt[QPB];
    __shared__ float smin[QPB][WPB][16];             // 2KB
    int tid = threadIdx.x;
    int lane = tid & 63;
    int w = tid >> 6;
    int qb = blockIdx.x * QPB;
    v2f Qx[QPB], Qy[QPB], Qz[QPB];
#pragma unroll
    for (int i = 0; i < QPB; ++i) {
        float4 t4 = pos4[qb + i];          // wave-uniform
        float ax = __frfl(t4.x), ay = __frfl(t4.y), az = __frfl(t4.z);
        Qx[i] = (v2f){ax, ax}; Qy[i] = (v2f){ay, ay}; Qz[i] = (v2f){az, az};
    }
    // per-lane float4 stream base: quarter = 32 groups * 128 float4
    const float4* pt = pm2t + (size_t)w * (GRPQ * 128) + lane;

    // ---- Phase A: packed per-lane minima, 2-deep prefetch (8 loads in flight) ----
    float mn[QPB];
#pragma unroll
    for (int i = 0; i < QPB; ++i) mn[i] = INFINITY;
    {
        float4 aXY0 = pt[0],   aZW0 = pt[64],  aXY1 = pt[128], aZW1 = pt[192];
        float4 bXY0 = pt[256], bZW0 = pt[320], bXY1 = pt[384], bZW1 = pt[448];
        int off = 512;
#pragma unroll 2
        for (int t = 0; t < NITER; ++t) {
            v2f X0 = {aXY0.x, aXY0.y}, Y0 = {aXY0.z, aXY0.w};
            v2f Z0 = {aZW0.x, aZW0.y}, W0 = {aZW0.z, aZW0.w};
            v2f X1 = {aXY1.x, aXY1.y}, Y1 = {aXY1.z, aXY1.w};
            v2f Z1 = {aZW1.x, aZW1.y}, W1 = {aZW1.z, aZW1.w};
#pragma unroll
            for (int i = 0; i < QPB; ++i) {
                v2f D0 = pdist(Qx[i], Qy[i], Qz[i], X0, Y0, Z0, W0);
                v2f D1 = pdist(Qx[i], Qy[i], Qz[i], X1, Y1, Z1, W1);
                mn[i] = fminf(mn[i], fminf(D0.x, D0.y));   // v_min3
                mn[i] = fminf(mn[i], fminf(D1.x, D1.y));   // v_min3
            }
            aXY0 = bXY0; aZW0 = bZW0; aXY1 = bXY1; aZW1 = bZW1;
            bXY0 = pt[off]; bZW0 = pt[off + 64]; bXY1 = pt[off + 128]; bZW1 = pt[off + 192];
            off += 256;   // pad keeps trailing prefetches in-bounds
        }
    }
    // per-wave stream minima (stream = lane mod 16) -> LDS
#pragma unroll
    for (int i = 0; i < QPB; ++i) {
        float m = mn[i];
        m = fminf(m, __shfl_xor(m, 16, 64));
        m = fminf(m, __shfl_xor(m, 32, 64));
        if (lane < 16) smin[i][w][lane] = m;
    }
    if (tid < QPB) knt[tid] = 0;
    __syncthreads();   // barrier 1: smin + knt visible

    // tight tau from full-N stream minima (combine the 4 wave quarters)
    float tq[QPB];
#pragma unroll
    for (int i = 0; i < QPB; ++i) {
        int s = lane & 15;
        float m = fminf(fminf(smin[i][0][s], smin[i][1][s]),
                        fminf(smin[i][2][s], smin[i][3][s]));
        m = fmaxf(m, __shfl_xor(m, 1, 64));
        m = fmaxf(m, __shfl_xor(m, 2, 64));
        m = fmaxf(m, __shfl_xor(m, 4, 64));
        m = fmaxf(m, __shfl_xor(m, 8, 64));
        tq[i] = __frfl(m);                  // wave-uniform -> SGPR
    }

    // ---- Phase B: tau-filtered push; one __any branch per query per iter ----
    {
        float4 aXY0 = pt[0],   aZW0 = pt[64],  aXY1 = pt[128], aZW1 = pt[192];
        float4 bXY0 = pt[256], bZW0 = pt[320], bXY1 = pt[384], bZW1 = pt[448];
        int off = 512;
        int pbase = w * (GRPQ * 64);        // pair-index base of quarter
#pragma unroll 2
        for (int t = 0; t < NITER; ++t) {
            v2f X0 = {aXY0.x, aXY0.y}, Y0 = {aXY0.z, aXY0.w};
            v2f Z0 = {aZW0.x, aZW0.y}, W0 = {aZW0.z, aZW0.w};
            v2f X1 = {aXY1.x, aXY1.y}, Y1 = {aXY1.z, aXY1.w};
            v2f Z1 = {aZW1.x, aZW1.y}, W1 = {aZW1.z, aZW1.w};
            int j00 = 2 * (pbase + t * 128 + lane);   // slot0: j00, j00+1
            int j10 = j00 + 128;                       // slot1: j10, j10+1
#pragma unroll
            for (int i = 0; i < QPB; ++i) {
                v2f D0 = pdist(Qx[i], Qy[i], Qz[i], X0, Y0, Z0, W0);
                v2f D1 = pdist(Qx[i], Qy[i], Qz[i], X1, Y1, Z1, W1);
                float m01 = fminf(fminf(D0.x, D0.y), fminf(D1.x, D1.y));
                if (__any(m01 <= tq[i])) {             // vccz skip, no exec dance
                    if (D0.x <= tq[i]) { int s = atomicAdd(&knt[i], 1); if (s < SCAP) keys[i][s] = dkey(D0.x, j00); }
                    if (D0.y <= tq[i]) { int s = atomicAdd(&knt[i], 1); if (s < SCAP) keys[i][s] = dkey(D0.y, j00 + 1); }
                    if (D1.x <= tq[i]) { int s = atomicAdd(&knt[i], 1); if (s < SCAP) keys[i][s] = dkey(D1.x, j10); }
                    if (D1.y <= tq[i]) { int s = atomicAdd(&knt[i], 1); if (s < SCAP) keys[i][s] = dkey(D1.y, j10 + 1); }
                }
            }
            aXY0 = bXY0; aZW0 = bZW0; aXY1 = bXY1; aZW1 = bZW1;
            bXY0 = pt[off]; bZW0 = pt[off + 64]; bXY1 = pt[off + 128]; bZW1 = pt[off + 448 - 256];
            bXY1 = pt[off + 128]; bZW1 = pt[off + 192];
            off += 256;
        }
    }
    __syncthreads();   // barrier 2: all pushes visible

    // ---- Extraction: wave w handles queries 2w, 2w+1; 8-wide rank loop ----
#pragma unroll
    for (int e = 0; e < 2; ++e) {
        int qi = w * 2 + e;
        int q = qb + qi;
        int ntot = knt[qi];
        if (ntot <= SCAP) {
            unsigned long long k0 = (lane < ntot) ? keys[qi][lane] : ~0ull;
            unsigned long long k1 = (lane + 64 < ntot) ? keys[qi][lane + 64] : ~0ull;
            int r0 = 0, r1 = 0;
            int t = 0;
            for (; t + 8 <= ntot; t += 8) {             // 8 independent ds_reads
                unsigned long long a0 = keys[qi][t + 0], a1 = keys[qi][t + 1];
                unsigned long long a2 = keys[qi][t + 2], a3 = keys[qi][t + 3];
                unsigned long long a4 = keys[qi][t + 4], a5 = keys[qi][t + 5];
                unsigned long long a6 = keys[qi][t + 6], a7 = keys[qi][t + 7];
                r0 += (int)(a0 < k0) + (int)(a1 < k0) + (int)(a2 < k0) + (int)(a3 < k0)
                    + (int)(a4 < k0) + (int)(a5 < k0) + (int)(a6 < k0) + (int)(a7 < k0);
                r1 += (int)(a0 < k1) + (int)(a1 < k1) + (int)(a2 < k1) + (int)(a3 < k1)
                    + (int)(a4 < k1) + (int)(a5 < k1) + (int)(a6 < k1) + (int)(a7 < k1);
            }
            for (; t < ntot; ++t) {
                unsigned long long k = keys[qi][t];
                r0 += (int)(k < k0);
                r1 += (int)(k < k1);
            }
            if (lane < ntot && r0 < KNN) idx[q * KNN + r0] = (int)(k0 & 0xffffffffu);
            if (lane + 64 < ntot && r1 < KNN) idx[q * KNN + r1] = (int)(k1 & 0xffffffffu);
        } else {
            // overflow (rare): exact full rescan, scalar chain bit-exact vs packed
            float tqq = tq[qi];
            float ax = Qx[qi].x, ay = Qy[qi].x, az = Qz[qi].x;
            unsigned long long key[16];
#pragma unroll
            for (int u = 0; u < 16; ++u) key[u] = ~0ull;
            for (int j = lane; j < NPTS; j += 64) {
                float v = distm2(ax, ay, az, pm2[j]);
                unsigned long long k = dkey(v, j);
                if (v <= tqq && k < key[15]) {
#pragma unroll
                    for (int s = 0; s < 16; ++s) {
                        unsigned long long a = k < key[s] ? k : key[s];
                        unsigned long long b = k < key[s] ? key[s] : k;
                        key[s] = a;
                        k = b;
                    }
                }
            }
            wave_top16_16(key, lane, q, idx);
        }
    }
}

// FUSED EdgeConv1 + ec2_pre (both pointwise in p; h1 never touches global).
__global__ __launch_bounds__(256) void ec12_kernel(const float4* __restrict__ pos4,
                                                   const int* __restrict__ idx,
                                                   const float* __restrict__ W1,
                                                   const float* __restrict__ b1,
                                                   const float* __restrict__ W2,
                                                   const float* __restrict__ b2,
                                                   float* __restrict__ C2,
                                                   float* __restrict__ Y2) {
    __shared__ float h1s[16][64];    // 4KB, [w*4+i][t], wave-private slices
    int t = threadIdx.x & 63;
    int w = threadIdx.x >> 6;
    int pb = blockIdx.x * 16 + w * 4;
    float w0 = W1[0 * HID + t], w1 = W1[1 * HID + t], w2 = W1[2 * HID + t];
    float v0 = W1[3 * HID + t], v1 = W1[4 * HID + t], v2 = W1[5 * HID + t];
    float bt1 = b1[t];
#pragma unroll
    for (int i = 0; i < 4; ++i) {
        int p = pb + i;
        float4 xi = pos4[p];
        float C = bt1 + xi.x * (w0 - v0) + xi.y * (w1 - v1) + xi.z * (w2 - v2);
        const int4* ip = (const int4*)(idx + (size_t)p * KNN);
        int4 n0 = ip[0], n1 = ip[1], n2 = ip[2], n3 = ip[3];   // 4 parallel loads
        int jj[16] = {n0.x, n0.y, n0.z, n0.w, n1.x, n1.y, n1.z, n1.w,
                      n2.x, n2.y, n2.z, n2.w, n3.x, n3.y, n3.z, n3.w};
        float m = -INFINITY;
#pragma unroll
        for (int k = 0; k < KNN; ++k) {
            float4 xj = pos4[jj[k]];      // 16 mutually-independent uniform loads
            m = fmaxf(m, fmaf(xj.x, v0, fmaf(xj.y, v1, xj.z * v2)));
        }
        h1s[w * 4 + i][t] = fmaxf(C + m, 0.f);
    }
    __syncthreads();
    float aa[4] = {0.f, 0.f, 0.f, 0.f};
    float ab[4] = {0.f, 0.f, 0.f, 0.f};
#pragma unroll 8
    for (int f = 0; f < 64; ++f) {
        float wa = W2[f * HID + t];
        float wb = W2[(64 + f) * HID + t];
#pragma unroll
        for (int i = 0; i < 4; ++i) {
            float h = h1s[w * 4 + i][f];   // broadcast ds_read
            aa[i] = fmaf(h, wa, aa[i]);
            ab[i] = fmaf(h, wb, ab[i]);
        }
    }
    float bt = b2[t];
#pragma unroll
    for (int i = 0; i < 4; ++i) {
        C2[(pb + i) * HID + t] = bt + aa[i] - ab[i];
        Y2[(pb + i) * HID + t] = ab[i];
    }
}

// ec2_maxpool: val = relu(C2 + max_k Y2[idx[k]]); block-partial max-pool.
__global__ __launch_bounds__(256) void ec2_maxpool_kernel(const float* __restrict__ C2,
                                                          const float* __restrict__ Y2,
                                                          const int* __restrict__ idx,
                                                          float* __restrict__ gpartial) {
    int t = threadIdx.x & 63;
    int lp = threadIdx.x >> 6;
    int p = blockIdx.x * 4 + lp;
    const int4* ip = (const int4*)(idx + (size_t)p * KNN);
    int4 n0 = ip[0], n1 = ip[1], n2 = ip[2], n3 = ip[3];
    int jj[16] = {n0.x, n0.y, n0.z, n0.w, n1.x, n1.y, n1.z, n1.w,
                  n2.x, n2.y, n2.z, n2.w, n3.x, n3.y, n3.z, n3.w};
    float m = -INFINITY;
#pragma unroll
    for (int k = 0; k < KNN; ++k) {
        m = fmaxf(m, Y2[jj[k] * HID + t]);   // 16 independent gathers
    }
    float val = fmaxf(C2[p * HID + t] + m, 0.f);
    __shared__ float red[4][64];
    red[lp][t] = val;
    __syncthreads();
    if (lp == 0) {
        float g = fmaxf(fmaxf(red[0][t], red[1][t]), fmaxf(red[2][t], red[3][t]));
        gpartial[blockIdx.x * 64 + t] = g;
    }
}

// greduce2: 4096 -> 256 partial rows, fully coalesced, 256 parallel blocks.
__global__ __launch_bounds__(256) void greduce2_kernel(const float* __restrict__ gpartial,
                                                       float* __restrict__ gp2) {
    __shared__ float red[4][64];
    int f = threadIdx.x & 63;
    int w = threadIdx.x >> 6;
    int r0 = blockIdx.x * 16 + w * 4;
    float m = -INFINITY;
#pragma unroll
    for (int r = 0; r < 4; ++r) m = fmaxf(m, gpartial[(r0 + r) * 64 + f]);
    red[w][f] = m;
    __syncthreads();
    if (w == 0)
        gp2[blockIdx.x * 64 + f] =
            fmaxf(fmaxf(red[0][f], red[1][f]), fmaxf(red[2][f], red[3][f]));
}

// tail2: 256 rows -> g[64], then linear head. One block (cheap now).
__global__ __launch_bounds__(256) void tail2_kernel(const float* __restrict__ gp2,
                                                    const float* __restrict__ Wc,
                                                    const float* __restrict__ bc,
                                                    float* __restrict__ out) {
    __shared__ float red[4][64];
    __shared__ float g[64];
    int f = threadIdx.x & 63;
    int w = threadIdx.x >> 6;
    float m = -INFINITY;
    for (int i = w; i < 256; i += 4) m = fmaxf(m, gp2[i * 64 + f]);
    red[w][f] = m;
    __syncthreads();
    if (w == 0) g[f] = fmaxf(fmaxf(red[0][f], red[1][f]), fmaxf(red[2][f], red[3][f]));
    __syncthreads();
    if (threadIdx.x < NCLS) {
        float a = bc[threadIdx.x];
#pragma unroll
        for (int h = 0; h < HID; ++h) a = fmaf(g[h], Wc[h * NCLS + threadIdx.x], a);
        out[threadIdx.x] = a;
    }
}

extern "C" void kernel_launch(void* const* d_in, const int* in_sizes, int n_in,
                              void* d_out, int out_size, void* d_ws, size_t ws_size,
                              hipStream_t stream) {
    const float* pos = (const float*)d_in[0];
    // d_in[1] = batch (all zeros, num_segments=1) -> unused
    const float* W1 = (const float*)d_in[2];
    const float* b1 = (const float*)d_in[3];
    const float* W2 = (const float*)d_in[4];
    const float* b2 = (const float*)d_in[5];
    const float* Wc = (const float*)d_in[6];
    const float* bc = (const float*)d_in[7];
    float* out = (float*)d_out;

    char* ws = (char*)d_ws;
    size_t o = 0;
    auto alloc = [&](size_t bytes) { size_t r = o; o += (bytes + 255) & ~size_t(255); return r; };
    size_t fm = (size_t)NPTS * HID * 4;
    size_t o_pos4 = alloc((size_t)NPTS * 16);
    size_t o_pm2 = alloc((size_t)NPTS * 16);
    size_t o_pm2t = alloc((size_t)(NPTS + TPAD) * 16);
    size_t o_idx = alloc((size_t)NPTS * KNN * 4);
    size_t o_C2 = alloc(fm);
    size_t o_Y2 = alloc(fm);
    size_t o_gp = alloc((size_t)(NPTS / 4) * HID * 4);
    size_t o_gp2 = alloc((size_t)256 * HID * 4);

    float4* pos4 = (float4*)(ws + o_pos4);
    float4* pm2 = (float4*)(ws + o_pm2);
    float4* pm2t = (float4*)(ws + o_pm2t);
    int* idx = (int*)(ws + o_idx);
    float* C2 = (float*)(ws + o_C2);
    float* Y2 = (float*)(ws + o_Y2);
    float* gp = (float*)(ws + o_gp);
    float* gp2 = (float*)(ws + o_gp2);

    // zero the pm2t prefetch pad (loaded but never consumed)
    hipMemsetAsync(pm2t + NPTS, 0, TPAD * sizeof(float4), stream);

    prep_kernel<<<NPTS / 256, 256, 0, stream>>>(pos, pos4, pm2, pm2t);
    knn_kernel<<<NPTS / QPB, 256, 0, stream>>>(pos4, pm2, pm2t, idx);
    ec12_kernel<<<NPTS / 16, 256, 0, stream>>>(pos4, idx, W1, b1, W2, b2, C2, Y2);
    ec2_maxpool_kernel<<<NPTS / 4, 256, 0, stream>>>(C2, Y2, idx, gp);
    greduce2_kernel<<<256, 256, 0, stream>>>(gp, gp2);
    tail2_kernel<<<1, 256, 0, stream>>>(gp2, Wc, bc, out);
}